// Round 6
// baseline (169.330 us; speedup 1.0000x reference)
//
#include <hip/hip_runtime.h>

// SeesawLoss forward, N=32768 rows, C=1203 classes (+2 binary logits).
// Round 6: round-5 math (fixed 2^-16 softmax shift, no max pass, analytic
// W bound, label exclusion by subtraction) +
//  - x4 shift-replicated P*log2(cum) table in LDS (20480 B exactly ->
//    8 blocks/CU; float4 ds_read_b128 table reads -> bank conflicts ~0;
//    round 5's scalar stride-4 reads were an 8-way conflict, 3.9M cycles)
//  - dual-row software pipeline: row n+stride's global loads issue before
//    row n's compute (round-4 structure WITHOUT the ordered-atomic fused
//    reduction that caused the round-4 regression)
//  - plogl folded into the exponent bound (1 VALU/elem saved in pass 2)
// 3 dispatches: prep (1-block hist + table), row kernel, tiny reduce.
// No float atomics, no ordered atomics.

#define C_CLS   1203
#define ROW_LEN 1205
#define NBINS   1204
#define RPAD    1280
#define NEG_HUGE (-3.402823466e38f)
#define LOG2E    1.4426950408889634f
#define LN2      0.6931471805599453f
#define LOG_EPS2 (-6.643856189774724f)   // log2(0.01)
#define P_POW    0.8f
#define Q_POW    2.0f
#define M2FIX    16.0f                   // fixed softmax shift (|logits| << 11)

#if __has_builtin(__builtin_amdgcn_exp2f)
#define EXP2(x) __builtin_amdgcn_exp2f(x)
#else
#define EXP2(x) exp2f(x)
#endif
#if __has_builtin(__builtin_amdgcn_logf)
#define LOG2F_(x) __builtin_amdgcn_logf(x)
#else
#define LOG2F_(x) __log2f(x)
#endif

// ---------------- dispatch 1: histogram + replicated P*log2(count) table ----
__launch_bounds__(1024)
__global__ void prep_k(const int* __restrict__ labels, int N,
                       float* __restrict__ plgG) {
    __shared__ unsigned hist[NBINS];
    for (int i = threadIdx.x; i < NBINS; i += 1024) hist[i] = 0u;
    __syncthreads();

    const int nv = N >> 2;
    const int4* lp = (const int4*)labels;
    for (int i = threadIdx.x; i < nv; i += 1024) {
        int4 v = lp[i];
        atomicAdd(&hist[v.x], 1u); atomicAdd(&hist[v.y], 1u);
        atomicAdd(&hist[v.z], 1u); atomicAdd(&hist[v.w], 1u);
    }
    for (int i = (N & ~3) + (int)threadIdx.x; i < N; i += 1024)
        atomicAdd(&hist[labels[i]], 1u);
    __syncthreads();

    // copy kk, entry u = P*log2(max(cum[u+kk],1)); 0 in the pad region
    for (int u = threadIdx.x; u < RPAD; u += 1024) {
        #pragma unroll
        for (int kk = 0; kk < 4; ++kk) {
            int j = u + kk;
            float v = 0.0f;
            if (j < NBINS) v = P_POW * LOG2F_(fmaxf((float)hist[j], 1.0f));
            plgG[kk * RPAD + u] = v;
        }
    }
}

// Vector-state loader: 5 float4 segments (segs 0-3 pure classes, seg 4
// masked) + prefix + wave-uniform labv/c0/c1 (label passed in, already
// pipelined by the caller).
#define LOADV(n_, label_, q_, pv_, labv_, c0_, c1_, k_) do {                    \
    const float* row_ = cls + (size_t)(n_) * ROW_LEN;                           \
    labv_ = row_[label_]; c0_ = row_[C_CLS]; c1_ = row_[C_CLS + 1];             \
    const float4* vp_ = (const float4*)(row_ + (k_));                           \
    _Pragma("unroll")                                                           \
    for (int i_ = 0; i_ < 4; ++i_) q_[i_] = vp_[(size_t)i_ * 64 + lane];        \
    {   int b4_ = (k_) + 1024 + 4 * lane;                                       \
        float4 t_ = make_float4(NEG_HUGE, NEG_HUGE, NEG_HUGE, NEG_HUGE);        \
        if (b4_ + 3 <= C_CLS - 1) { t_ = vp_[(size_t)256 + lane]; }             \
        else { if (b4_     <= C_CLS - 1) t_.x = row_[b4_];                      \
               if (b4_ + 1 <= C_CLS - 1) t_.y = row_[b4_ + 1];                  \
               if (b4_ + 2 <= C_CLS - 1) t_.z = row_[b4_ + 2]; }                \
        q_[4] = t_; }                                                           \
    pv_ = (lane < (k_)) ? row_[lane] : NEG_HUGE;                                \
} while (0)

// ---------------- dispatch 2: per-row loss, one wave per row ----------------
__launch_bounds__(256, 8)   // <=64 VGPR target: 8 waves/SIMD, 32 waves/CU
__global__ void seesaw_row_k(const float* __restrict__ cls,
                             const int* __restrict__ labels,
                             const float* __restrict__ lweights,
                             const float* __restrict__ plgG,
                             float* __restrict__ wsums,
                             int N) {
    __shared__ __align__(16) float plg[4][RPAD];   // 20480 B exactly
    {
        const float4* src = (const float4*)plgG;
        float4* dst = (float4*)&plg[0][0];
        for (int i = threadIdx.x; i < RPAD; i += 256) dst[i] = src[i];
    }
    __syncthreads();

    const int lane = threadIdx.x & 63;
    const int wv   = threadIdx.x >> 6;
    const int wid  = blockIdx.x * 4 + wv;
    const int nw   = gridDim.x * 4;        // multiple of 4 -> k wave-invariant

    float acc = 0.0f;
    int n = wid;
    if (n < N) {
        const int k = (-n) & 3;            // row base % 4 == n % 4 (1205%4==1)
        int   labc = labels[n];
        float wc   = lweights[n];
        float4 q[5]; float pv, labv, c0, c1;
        LOADV(n, labc, q, pv, labv, c0, c1, k);

        for (;;) {
            // ---- prefetch next row (loads retire under this row's compute)
            const int  n2    = n + nw;
            const bool have2 = (n2 < N);
            float4 qn[5]; float pvn, labvn, c0n, c1n; int labn; float wn;
            if (have2) {
                labn = labels[n2]; wn = lweights[n2];
                LOADV(n2, labn, qn, pvn, labvn, c0n, c1n, k);
            }

            // ---- pass 1: log2 domain in place, s = sum 2^(xl - 16)
            pv *= LOG2E;
            float s = EXP2(pv - M2FIX);
            #pragma unroll
            for (int i = 0; i < 5; ++i) {
                q[i].x *= LOG2E; q[i].y *= LOG2E;
                q[i].z *= LOG2E; q[i].w *= LOG2E;
                s += EXP2(q[i].x - M2FIX) + EXP2(q[i].y - M2FIX)
                   + EXP2(q[i].z - M2FIX) + EXP2(q[i].w - M2FIX);
            }
            #pragma unroll
            for (int o = 32; o > 0; o >>= 1) s += __shfl_xor(s, o, 64);

            const float L2    = M2FIX + LOG2F_(s);
            const float labv2 = labv * LOG2E;
            const float G     = fmaxf(labv2, L2 + LOG_EPS2);  // L2 + logsm2
            const float W     = L2 + Q_POW * (L2 - G);        // >= max adj
            const float plogl = plg[0][labc];
            const float Wp    = W + plogl;
            const float mW    = -W;

            // ---- pass 2: T = sum 2^(adj - W); label term subtracted after
            // t = min(lg - Wp, -W) == min(lg - plogl, 0) - W
            float T;
            {
                float t = fminf(plg[0][lane] - Wp, mW);
                float h = fmaxf(pv - G, 0.0f);
                T = EXP2(fmaf(Q_POW, h, pv) + t);
            }
            #pragma unroll
            for (int i = 0; i < 5; ++i) {
                const float4 lg = *(const float4*)&plg[k][256 * i + 4 * lane];
                { float t = fminf(lg.x - Wp, mW), h = fmaxf(q[i].x - G, 0.f);
                  T += EXP2(fmaf(Q_POW, h, q[i].x) + t); }
                { float t = fminf(lg.y - Wp, mW), h = fmaxf(q[i].y - G, 0.f);
                  T += EXP2(fmaf(Q_POW, h, q[i].y) + t); }
                { float t = fminf(lg.z - Wp, mW), h = fmaxf(q[i].z - G, 0.f);
                  T += EXP2(fmaf(Q_POW, h, q[i].z) + t); }
                { float t = fminf(lg.w - Wp, mW), h = fmaxf(q[i].w - G, 0.f);
                  T += EXP2(fmaf(Q_POW, h, q[i].w) + t); }
            }
            #pragma unroll
            for (int o = 32; o > 0; o >>= 1) T += __shfl_xor(T, o, 64);
            T -= EXP2(labv2 - W);     // adj[label] == csc[label] exactly
            T = fmaxf(T, 1e-37f);

            // ---- per-row tail (wave-uniform)
            const float nl2 = W + LOG2F_(T);
            const float xx  = (nl2 - labv2) * LN2;
            const float rl  = (xx > 0.0f) ? (xx + log1pf(__expf(-xx)))
                                          : log1pf(__expf(xx));
            const float mm   = fmaxf(c0, c1);
            const float lseb = mm + __logf(__expf(c0 - mm) + __expf(c1 - mm));
            const float ce   = lseb - ((labc == C_CLS) ? c1 : c0);
            const float rlw  = (wc == 1.0f) ? rl : 0.0f;   // pos_mask == 1.0
            acc += rlw + ce * wc;

            if (!have2) break;
            n = n2; labc = labn; wc = wn;
            labv = labvn; c0 = c0n; c1 = c1n; pv = pvn;
            #pragma unroll
            for (int i = 0; i < 5; ++i) q[i] = qn[i];
        }
    }

    if (lane == 0) wsums[wid] = acc;   // per-wave partial, plain store
}

// ---------------- dispatch 3: deterministic final sum ----------------
__launch_bounds__(512)
__global__ void reduce_k(const float* __restrict__ wsums, int nb,
                         const int* __restrict__ avg_raw,
                         float* __restrict__ out) {
    int tid = threadIdx.x;
    float s = 0.0f;
    int nb4 = nb >> 2;
    const float4* bp = (const float4*)wsums;
    for (int i = tid; i < nb4; i += 512) {
        float4 v = bp[i];
        s += (v.x + v.y) + (v.z + v.w);
    }
    for (int i = (nb4 << 2) + tid; i < nb; i += 512) s += wsums[i];

    #pragma unroll
    for (int o = 32; o > 0; o >>= 1) s += __shfl_xor(s, o, 64);

    __shared__ float ws8[8];
    int lane = tid & 63, wvi = tid >> 6;
    if (lane == 0) ws8[wvi] = s;
    __syncthreads();
    if (tid == 0) {
        float t = 0.0f;
        #pragma unroll
        for (int i = 0; i < 8; ++i) t += ws8[i];
        int ai = avg_raw[0];
        float af;
        if (ai > 0 && ai < (1 << 26)) {
            af = (float)ai;              // stored as integer
        } else {
            union { int i; float f; } u; // stored as float bits
            u.i = ai;
            af = u.f;
        }
        out[0] = t / af;
    }
}

extern "C" void kernel_launch(void* const* d_in, const int* in_sizes, int n_in,
                              void* d_out, int out_size, void* d_ws, size_t ws_size,
                              hipStream_t stream) {
    const float* cls    = (const float*)d_in[0];
    const int*   labels = (const int*)d_in[1];
    const float* lw     = (const float*)d_in[2];
    const int*   avgp   = (const int*)d_in[3];
    float*       out    = (float*)d_out;

    const int N = in_sizes[1];

    // ws layout: [ float plgG[4*RPAD] | float wsums[g*4] ]
    float* plgG  = (float*)d_ws;
    float* wsums = (float*)d_ws + 4 * RPAD;

    int g = (N + 15) / 16;               // 4 waves/block * 4 rows/wave
    if (g > 2048) g = 2048;
    if (g < 1) g = 1;

    prep_k<<<1, 1024, 0, stream>>>(labels, N, plgG);
    seesaw_row_k<<<g, 256, 0, stream>>>(cls, labels, lw, plgG, wsums, N);
    reduce_k<<<1, 512, 0, stream>>>(wsums, g * 4, avgp, out);
}

// Round 7
// 86.172 us; speedup vs baseline: 1.9650x; 1.9650x over previous
//
#include <hip/hip_runtime.h>

// SeesawLoss forward, N=32768 rows, C=1203 classes (+2 binary logits).
// Round 7 = round 5's single-row structure (32 VGPR, no spill, 32 waves/CU)
// with ONLY the LDS table access changed:
//  - x4 shift-replicated P*log2(cum) table (20480 B exactly -> 8 blocks/CU),
//    read as 16B-aligned ds_read_b128 (offset 5120k+1024i+16*lane) ->
//    conflict-free (round 5's scalar stride-4 reads were 8-way, 3.9M cycles).
// Round 6's lesson applied: NO register-resident row prefetch under a
// __launch_bounds__ VGPR cap (it spilled: 282 MB fetch + 264 MB write of
// scratch traffic per dispatch). Latency is hidden by TLP alone.
// 3 dispatches: prep (1-block hist + table), row kernel, tiny reduce.
// No float atomics, no ordered atomics.

#define C_CLS   1203
#define ROW_LEN 1205
#define NBINS   1204
#define RPAD    1280
#define NEG_HUGE (-3.402823466e38f)
#define LOG2E    1.4426950408889634f
#define LN2      0.6931471805599453f
#define LOG_EPS2 (-6.643856189774724f)   // log2(0.01)
#define P_POW    0.8f
#define Q_POW    2.0f
#define M2FIX    16.0f                   // fixed softmax shift (|logits| << 11)

#if __has_builtin(__builtin_amdgcn_exp2f)
#define EXP2(x) __builtin_amdgcn_exp2f(x)
#else
#define EXP2(x) exp2f(x)
#endif
#if __has_builtin(__builtin_amdgcn_logf)
#define LOG2F_(x) __builtin_amdgcn_logf(x)
#else
#define LOG2F_(x) __log2f(x)
#endif

// ---------------- dispatch 1: histogram + replicated P*log2(count) table ----
__launch_bounds__(1024)
__global__ void prep_k(const int* __restrict__ labels, int N,
                       float* __restrict__ plgG) {
    __shared__ unsigned hist[NBINS];
    for (int i = threadIdx.x; i < NBINS; i += 1024) hist[i] = 0u;
    __syncthreads();

    const int nv = N >> 2;
    const int4* lp = (const int4*)labels;
    for (int i = threadIdx.x; i < nv; i += 1024) {
        int4 v = lp[i];
        atomicAdd(&hist[v.x], 1u); atomicAdd(&hist[v.y], 1u);
        atomicAdd(&hist[v.z], 1u); atomicAdd(&hist[v.w], 1u);
    }
    for (int i = (N & ~3) + (int)threadIdx.x; i < N; i += 1024)
        atomicAdd(&hist[labels[i]], 1u);
    __syncthreads();

    // copy kk, entry u = P*log2(max(cum[u+kk],1)); 0 in the pad region
    for (int u = threadIdx.x; u < RPAD; u += 1024) {
        #pragma unroll
        for (int kk = 0; kk < 4; ++kk) {
            int j = u + kk;
            float v = 0.0f;
            if (j < NBINS) v = P_POW * LOG2F_(fmaxf((float)hist[j], 1.0f));
            plgG[kk * RPAD + u] = v;
        }
    }
}

// ---------------- dispatch 2: per-row loss, one wave per row ----------------
__launch_bounds__(256, 8)   // single-row state fits easily in 64 VGPR
__global__ void seesaw_row_k(const float* __restrict__ cls,
                             const int* __restrict__ labels,
                             const float* __restrict__ lweights,
                             const float* __restrict__ plgG,
                             float* __restrict__ wsums,
                             int N) {
    __shared__ __align__(16) float plg[4][RPAD];   // 20480 B exactly
    {
        const float4* src = (const float4*)plgG;
        float4* dst = (float4*)&plg[0][0];
        for (int i = threadIdx.x; i < RPAD; i += 256) dst[i] = src[i];
    }
    __syncthreads();

    const int lane = threadIdx.x & 63;
    const int wv   = threadIdx.x >> 6;
    const int wid  = blockIdx.x * 4 + wv;
    const int nw   = gridDim.x * 4;        // multiple of 4 -> k wave-invariant

    float acc = 0.0f;
    int n = wid;
    if (n < N) {
        const int k = (-n) & 3;            // row base % 4 == n % 4 (1205%4==1)
        // scalar-only pipeline: labels/weights one row ahead (breaks the
        // labels[n] -> row[label] dependent-load chain; 2 registers, no spill)
        int   labc = labels[n];
        float wc   = lweights[n];

        for (;;) {
            const int  n2    = n + nw;
            const bool have2 = (n2 < N);
            int labn = 0; float wn = 0.0f;
            if (have2) { labn = labels[n2]; wn = lweights[n2]; }

            const float* row = cls + (size_t)n * ROW_LEN;
            const float labv = row[labc];
            const float c0   = row[C_CLS];
            const float c1   = row[C_CLS + 1];

            // ---- row load: prefix + 5 float4 segments (segs 0-3 pure classes)
            const float4* vp = (const float4*)(row + k);
            float4 q[5];
            #pragma unroll
            for (int i = 0; i < 4; ++i) q[i] = vp[(size_t)i * 64 + lane];
            {
                int b4 = k + 1024 + 4 * lane;
                float4 t = make_float4(NEG_HUGE, NEG_HUGE, NEG_HUGE, NEG_HUGE);
                if (b4 + 3 <= C_CLS - 1) {
                    t = vp[(size_t)256 + lane];
                } else {
                    if (b4     <= C_CLS - 1) t.x = row[b4];
                    if (b4 + 1 <= C_CLS - 1) t.y = row[b4 + 1];
                    if (b4 + 2 <= C_CLS - 1) t.z = row[b4 + 2];
                }
                q[4] = t;
            }
            float pv = (lane < k) ? row[lane] : NEG_HUGE;

            // ---- pass 1: log2 domain in place, s = sum 2^(xl - 16)
            // (no max pass: logits bounded, 2^(xl-16) can't overflow/vanish)
            pv *= LOG2E;
            float s = EXP2(pv - M2FIX);
            #pragma unroll
            for (int i = 0; i < 5; ++i) {
                q[i].x *= LOG2E; q[i].y *= LOG2E;
                q[i].z *= LOG2E; q[i].w *= LOG2E;
                s += EXP2(q[i].x - M2FIX) + EXP2(q[i].y - M2FIX)
                   + EXP2(q[i].z - M2FIX) + EXP2(q[i].w - M2FIX);
            }
            #pragma unroll
            for (int o = 32; o > 0; o >>= 1) s += __shfl_xor(s, o, 64);

            const float L2    = M2FIX + LOG2F_(s);
            const float labv2 = labv * LOG2E;
            const float G     = fmaxf(labv2, L2 + LOG_EPS2);  // L2 + logsm2
            const float W     = L2 + Q_POW * (L2 - G);        // >= max adj
            const float plogl = plg[0][labc];
            const float Wp    = W + plogl;
            const float mW    = -W;

            // ---- pass 2: T = sum 2^(adj - W); label term subtracted after
            // t = min(lg - Wp, -W) == min(lg - plogl, 0) - W
            float T;
            {
                float t = fminf(plg[0][lane] - Wp, mW);
                float h = fmaxf(pv - G, 0.0f);
                T = EXP2(fmaf(Q_POW, h, pv) + t);
            }
            #pragma unroll
            for (int i = 0; i < 5; ++i) {
                // 16B-aligned conflict-free ds_read_b128 for any k
                const float4 lg = *(const float4*)&plg[k][256 * i + 4 * lane];
                { float t = fminf(lg.x - Wp, mW), h = fmaxf(q[i].x - G, 0.f);
                  T += EXP2(fmaf(Q_POW, h, q[i].x) + t); }
                { float t = fminf(lg.y - Wp, mW), h = fmaxf(q[i].y - G, 0.f);
                  T += EXP2(fmaf(Q_POW, h, q[i].y) + t); }
                { float t = fminf(lg.z - Wp, mW), h = fmaxf(q[i].z - G, 0.f);
                  T += EXP2(fmaf(Q_POW, h, q[i].z) + t); }
                { float t = fminf(lg.w - Wp, mW), h = fmaxf(q[i].w - G, 0.f);
                  T += EXP2(fmaf(Q_POW, h, q[i].w) + t); }
            }
            #pragma unroll
            for (int o = 32; o > 0; o >>= 1) T += __shfl_xor(T, o, 64);
            T -= EXP2(labv2 - W);     // adj[label] == csc[label] exactly
            T = fmaxf(T, 1e-37f);

            // ---- per-row tail (wave-uniform)
            const float nl2 = W + LOG2F_(T);
            const float xx  = (nl2 - labv2) * LN2;
            const float rl  = (xx > 0.0f) ? (xx + log1pf(__expf(-xx)))
                                          : log1pf(__expf(xx));
            const float mm   = fmaxf(c0, c1);
            const float lseb = mm + __logf(__expf(c0 - mm) + __expf(c1 - mm));
            const float ce   = lseb - ((labc == C_CLS) ? c1 : c0);
            const float rlw  = (wc == 1.0f) ? rl : 0.0f;   // pos_mask == 1.0
            acc += rlw + ce * wc;

            if (!have2) break;
            n = n2; labc = labn; wc = wn;
        }
    }

    if (lane == 0) wsums[wid] = acc;   // per-wave partial, plain store
}

// ---------------- dispatch 3: deterministic final sum ----------------
__launch_bounds__(512)
__global__ void reduce_k(const float* __restrict__ wsums, int nb,
                         const int* __restrict__ avg_raw,
                         float* __restrict__ out) {
    int tid = threadIdx.x;
    float s = 0.0f;
    int nb4 = nb >> 2;
    const float4* bp = (const float4*)wsums;
    for (int i = tid; i < nb4; i += 512) {
        float4 v = bp[i];
        s += (v.x + v.y) + (v.z + v.w);
    }
    for (int i = (nb4 << 2) + tid; i < nb; i += 512) s += wsums[i];

    #pragma unroll
    for (int o = 32; o > 0; o >>= 1) s += __shfl_xor(s, o, 64);

    __shared__ float ws8[8];
    int lane = tid & 63, wvi = tid >> 6;
    if (lane == 0) ws8[wvi] = s;
    __syncthreads();
    if (tid == 0) {
        float t = 0.0f;
        #pragma unroll
        for (int i = 0; i < 8; ++i) t += ws8[i];
        int ai = avg_raw[0];
        float af;
        if (ai > 0 && ai < (1 << 26)) {
            af = (float)ai;              // stored as integer
        } else {
            union { int i; float f; } u; // stored as float bits
            u.i = ai;
            af = u.f;
        }
        out[0] = t / af;
    }
}

extern "C" void kernel_launch(void* const* d_in, const int* in_sizes, int n_in,
                              void* d_out, int out_size, void* d_ws, size_t ws_size,
                              hipStream_t stream) {
    const float* cls    = (const float*)d_in[0];
    const int*   labels = (const int*)d_in[1];
    const float* lw     = (const float*)d_in[2];
    const int*   avgp   = (const int*)d_in[3];
    float*       out    = (float*)d_out;

    const int N = in_sizes[1];

    // ws layout: [ float plgG[4*RPAD] | float wsums[g*4] ]
    float* plgG  = (float*)d_ws;
    float* wsums = (float*)d_ws + 4 * RPAD;

    int g = (N + 15) / 16;               // 4 waves/block * 4 rows/wave
    if (g > 2048) g = 2048;
    if (g < 1) g = 1;

    prep_k<<<1, 1024, 0, stream>>>(labels, N, plgG);
    seesaw_row_k<<<g, 256, 0, stream>>>(cls, labels, lw, plgG, wsums, N);
    reduce_k<<<1, 512, 0, stream>>>(wsums, g * 4, avgp, out);
}

// Round 8
// 50.860 us; speedup vs baseline: 3.3293x; 1.6943x over previous
//
#include <hip/hip_runtime.h>

// SeesawLoss forward, N=32768 rows, C=1203 classes (+2 binary logits).
// Round 8 = round 7 with ONE change: __launch_bounds__(256) WITHOUT the
// min-waves clause on the row kernel.
// Evidence: (256,8) drove the allocator to a 32-VGPR target in rounds 5-7;
// the ~20-float/lane row state spilled to scratch (round 7: 87.7 MB of HBM
// writes per warm dispatch vs 32 KB legitimate). Natural allocation
// (~48-64 VGPR) keeps 8 waves/SIMD with zero scratch.
// Kept from round 7: x4 shift-replicated P*log2(cum) table (20480 B LDS,
// 8 blocks/CU, 16B-aligned ds_read_b128 -> 0 bank conflicts), fixed 2^-16
// softmax shift (no max pass), analytic W bound (no 2nd max pass), label
// exclusion by subtraction, scalar-only label/weight pipeline.
// 3 dispatches: prep (1-block hist + table), row kernel, tiny reduce.
// No float atomics, no ordered atomics.

#define C_CLS   1203
#define ROW_LEN 1205
#define NBINS   1204
#define RPAD    1280
#define NEG_HUGE (-3.402823466e38f)
#define LOG2E    1.4426950408889634f
#define LN2      0.6931471805599453f
#define LOG_EPS2 (-6.643856189774724f)   // log2(0.01)
#define P_POW    0.8f
#define Q_POW    2.0f
#define M2FIX    16.0f                   // fixed softmax shift (|logits| << 11)

#if __has_builtin(__builtin_amdgcn_exp2f)
#define EXP2(x) __builtin_amdgcn_exp2f(x)
#else
#define EXP2(x) exp2f(x)
#endif
#if __has_builtin(__builtin_amdgcn_logf)
#define LOG2F_(x) __builtin_amdgcn_logf(x)
#else
#define LOG2F_(x) __log2f(x)
#endif

// ---------------- dispatch 1: histogram + replicated P*log2(count) table ----
__launch_bounds__(1024)
__global__ void prep_k(const int* __restrict__ labels, int N,
                       float* __restrict__ plgG) {
    __shared__ unsigned hist[NBINS];
    for (int i = threadIdx.x; i < NBINS; i += 1024) hist[i] = 0u;
    __syncthreads();

    const int nv = N >> 2;
    const int4* lp = (const int4*)labels;
    for (int i = threadIdx.x; i < nv; i += 1024) {
        int4 v = lp[i];
        atomicAdd(&hist[v.x], 1u); atomicAdd(&hist[v.y], 1u);
        atomicAdd(&hist[v.z], 1u); atomicAdd(&hist[v.w], 1u);
    }
    for (int i = (N & ~3) + (int)threadIdx.x; i < N; i += 1024)
        atomicAdd(&hist[labels[i]], 1u);
    __syncthreads();

    // copy kk, entry u = P*log2(max(cum[u+kk],1)); 0 in the pad region
    for (int u = threadIdx.x; u < RPAD; u += 1024) {
        #pragma unroll
        for (int kk = 0; kk < 4; ++kk) {
            int j = u + kk;
            float v = 0.0f;
            if (j < NBINS) v = P_POW * LOG2F_(fmaxf((float)hist[j], 1.0f));
            plgG[kk * RPAD + u] = v;
        }
    }
}

// ---------------- dispatch 2: per-row loss, one wave per row ----------------
__launch_bounds__(256)   // NO min-waves clause: let VGPRs float, forbid spill
__global__ void seesaw_row_k(const float* __restrict__ cls,
                             const int* __restrict__ labels,
                             const float* __restrict__ lweights,
                             const float* __restrict__ plgG,
                             float* __restrict__ wsums,
                             int N) {
    __shared__ __align__(16) float plg[4][RPAD];   // 20480 B exactly
    {
        const float4* src = (const float4*)plgG;
        float4* dst = (float4*)&plg[0][0];
        for (int i = threadIdx.x; i < RPAD; i += 256) dst[i] = src[i];
    }
    __syncthreads();

    const int lane = threadIdx.x & 63;
    const int wv   = threadIdx.x >> 6;
    const int wid  = blockIdx.x * 4 + wv;
    const int nw   = gridDim.x * 4;        // multiple of 4 -> k wave-invariant

    float acc = 0.0f;
    int n = wid;
    if (n < N) {
        const int k = (-n) & 3;            // row base % 4 == n % 4 (1205%4==1)
        // scalar-only pipeline: labels/weights one row ahead (breaks the
        // labels[n] -> row[label] dependent-load chain; 2 registers, no spill)
        int   labc = labels[n];
        float wc   = lweights[n];

        for (;;) {
            const int  n2    = n + nw;
            const bool have2 = (n2 < N);
            int labn = 0; float wn = 0.0f;
            if (have2) { labn = labels[n2]; wn = lweights[n2]; }

            const float* row = cls + (size_t)n * ROW_LEN;
            const float labv = row[labc];
            const float c0   = row[C_CLS];
            const float c1   = row[C_CLS + 1];

            // ---- row load: prefix + 5 float4 segments (segs 0-3 pure classes)
            const float4* vp = (const float4*)(row + k);
            float4 q[5];
            #pragma unroll
            for (int i = 0; i < 4; ++i) q[i] = vp[(size_t)i * 64 + lane];
            {
                int b4 = k + 1024 + 4 * lane;
                float4 t = make_float4(NEG_HUGE, NEG_HUGE, NEG_HUGE, NEG_HUGE);
                if (b4 + 3 <= C_CLS - 1) {
                    t = vp[(size_t)256 + lane];
                } else {
                    if (b4     <= C_CLS - 1) t.x = row[b4];
                    if (b4 + 1 <= C_CLS - 1) t.y = row[b4 + 1];
                    if (b4 + 2 <= C_CLS - 1) t.z = row[b4 + 2];
                }
                q[4] = t;
            }
            float pv = (lane < k) ? row[lane] : NEG_HUGE;

            // ---- pass 1: log2 domain in place, s = sum 2^(xl - 16)
            // (no max pass: logits bounded, 2^(xl-16) can't overflow/vanish)
            pv *= LOG2E;
            float s = EXP2(pv - M2FIX);
            #pragma unroll
            for (int i = 0; i < 5; ++i) {
                q[i].x *= LOG2E; q[i].y *= LOG2E;
                q[i].z *= LOG2E; q[i].w *= LOG2E;
                s += EXP2(q[i].x - M2FIX) + EXP2(q[i].y - M2FIX)
                   + EXP2(q[i].z - M2FIX) + EXP2(q[i].w - M2FIX);
            }
            #pragma unroll
            for (int o = 32; o > 0; o >>= 1) s += __shfl_xor(s, o, 64);

            const float L2    = M2FIX + LOG2F_(s);
            const float labv2 = labv * LOG2E;
            const float G     = fmaxf(labv2, L2 + LOG_EPS2);  // L2 + logsm2
            const float W     = L2 + Q_POW * (L2 - G);        // >= max adj
            const float plogl = plg[0][labc];
            const float Wp    = W + plogl;
            const float mW    = -W;

            // ---- pass 2: T = sum 2^(adj - W); label term subtracted after
            // t = min(lg - Wp, -W) == min(lg - plogl, 0) - W
            float T;
            {
                float t = fminf(plg[0][lane] - Wp, mW);
                float h = fmaxf(pv - G, 0.0f);
                T = EXP2(fmaf(Q_POW, h, pv) + t);
            }
            #pragma unroll
            for (int i = 0; i < 5; ++i) {
                // 16B-aligned conflict-free ds_read_b128 for any k
                const float4 lg = *(const float4*)&plg[k][256 * i + 4 * lane];
                { float t = fminf(lg.x - Wp, mW), h = fmaxf(q[i].x - G, 0.f);
                  T += EXP2(fmaf(Q_POW, h, q[i].x) + t); }
                { float t = fminf(lg.y - Wp, mW), h = fmaxf(q[i].y - G, 0.f);
                  T += EXP2(fmaf(Q_POW, h, q[i].y) + t); }
                { float t = fminf(lg.z - Wp, mW), h = fmaxf(q[i].z - G, 0.f);
                  T += EXP2(fmaf(Q_POW, h, q[i].z) + t); }
                { float t = fminf(lg.w - Wp, mW), h = fmaxf(q[i].w - G, 0.f);
                  T += EXP2(fmaf(Q_POW, h, q[i].w) + t); }
            }
            #pragma unroll
            for (int o = 32; o > 0; o >>= 1) T += __shfl_xor(T, o, 64);
            T -= EXP2(labv2 - W);     // adj[label] == csc[label] exactly
            T = fmaxf(T, 1e-37f);

            // ---- per-row tail (wave-uniform)
            const float nl2 = W + LOG2F_(T);
            const float xx  = (nl2 - labv2) * LN2;
            const float rl  = (xx > 0.0f) ? (xx + log1pf(__expf(-xx)))
                                          : log1pf(__expf(xx));
            const float mm   = fmaxf(c0, c1);
            const float lseb = mm + __logf(__expf(c0 - mm) + __expf(c1 - mm));
            const float ce   = lseb - ((labc == C_CLS) ? c1 : c0);
            const float rlw  = (wc == 1.0f) ? rl : 0.0f;   // pos_mask == 1.0
            acc += rlw + ce * wc;

            if (!have2) break;
            n = n2; labc = labn; wc = wn;
        }
    }

    if (lane == 0) wsums[wid] = acc;   // per-wave partial, plain store
}

// ---------------- dispatch 3: deterministic final sum ----------------
__launch_bounds__(512)
__global__ void reduce_k(const float* __restrict__ wsums, int nb,
                         const int* __restrict__ avg_raw,
                         float* __restrict__ out) {
    int tid = threadIdx.x;
    float s = 0.0f;
    int nb4 = nb >> 2;
    const float4* bp = (const float4*)wsums;
    for (int i = tid; i < nb4; i += 512) {
        float4 v = bp[i];
        s += (v.x + v.y) + (v.z + v.w);
    }
    for (int i = (nb4 << 2) + tid; i < nb; i += 512) s += wsums[i];

    #pragma unroll
    for (int o = 32; o > 0; o >>= 1) s += __shfl_xor(s, o, 64);

    __shared__ float ws8[8];
    int lane = tid & 63, wvi = tid >> 6;
    if (lane == 0) ws8[wvi] = s;
    __syncthreads();
    if (tid == 0) {
        float t = 0.0f;
        #pragma unroll
        for (int i = 0; i < 8; ++i) t += ws8[i];
        int ai = avg_raw[0];
        float af;
        if (ai > 0 && ai < (1 << 26)) {
            af = (float)ai;              // stored as integer
        } else {
            union { int i; float f; } u; // stored as float bits
            u.i = ai;
            af = u.f;
        }
        out[0] = t / af;
    }
}

extern "C" void kernel_launch(void* const* d_in, const int* in_sizes, int n_in,
                              void* d_out, int out_size, void* d_ws, size_t ws_size,
                              hipStream_t stream) {
    const float* cls    = (const float*)d_in[0];
    const int*   labels = (const int*)d_in[1];
    const float* lw     = (const float*)d_in[2];
    const int*   avgp   = (const int*)d_in[3];
    float*       out    = (float*)d_out;

    const int N = in_sizes[1];

    // ws layout: [ float plgG[4*RPAD] | float wsums[g*4] ]
    float* plgG  = (float*)d_ws;
    float* wsums = (float*)d_ws + 4 * RPAD;

    int g = (N + 15) / 16;               // 4 waves/block * 4 rows/wave
    if (g > 2048) g = 2048;
    if (g < 1) g = 1;

    prep_k<<<1, 1024, 0, stream>>>(labels, N, plgG);
    seesaw_row_k<<<g, 256, 0, stream>>>(cls, labels, lw, plgG, wsums, N);
    reduce_k<<<1, 512, 0, stream>>>(wsums, g * 4, avgp, out);
}